// Round 1
// baseline (379.758 us; speedup 1.0000x reference)
//
#include <hip/hip_runtime.h>
#include <hip/hip_bf16.h>

// KL(N(mu_p, diag(exp(ls_p))) || N(mu_q, diag(exp(ls_q)))), closed form,
// reduced to a single scalar:
//   out = 0.5 * ( S / N_samples - d )
// where S = sum over ALL elements of
//   elem = (ls_q - ls_p) + exp(ls_p - ls_q) + (m_q - m_p)^2 * exp(-ls_q)
// Shapes: (2, 3, 160, 192, 160) fp32. N_total = 29,491,200 (divisible by 4).
// N_samples = N_total / d = 9,830,400, d = 3.
//
// Memory-bound: 4 arrays * 118 MB = 472 MB read -> ~75 us at 6.3 TB/s.
// Strategy: float4 grid-stride loads, fp64 per-thread accumulate, wave
// shuffle reduce (64 lanes), LDS across waves, one double partial per block
// into d_ws, then a single-block finalize kernel.

#define BLOCKS   2048
#define THREADS  256

__global__ __launch_bounds__(THREADS) void kl_reduce_kernel(
    const float4* __restrict__ mp, const float4* __restrict__ lsp,
    const float4* __restrict__ mq, const float4* __restrict__ lsq,
    double* __restrict__ partials, long n4)
{
    double acc = 0.0;
    long stride = (long)gridDim.x * blockDim.x;
    for (long i = (long)blockIdx.x * blockDim.x + threadIdx.x; i < n4; i += stride) {
        float4 a = mp[i];
        float4 b = lsp[i];
        float4 c = mq[i];
        float4 d = lsq[i];

        float dx = c.x - a.x, dy = c.y - a.y, dz = c.z - a.z, dw = c.w - a.w;
        float eqx = __expf(-d.x), eqy = __expf(-d.y), eqz = __expf(-d.z), eqw = __expf(-d.w);
        float epx = __expf(b.x), epy = __expf(b.y), epz = __expf(b.z), epw = __expf(b.w);

        float e0 = (d.x - b.x) + epx * eqx + dx * dx * eqx;
        float e1 = (d.y - b.y) + epy * eqy + dy * dy * eqy;
        float e2 = (d.z - b.z) + epz * eqz + dz * dz * eqz;
        float e3 = (d.w - b.w) + epw * eqw + dw * dw * eqw;

        acc += (double)((e0 + e1) + (e2 + e3));
    }

    // wave (64-lane) reduction
    #pragma unroll
    for (int off = 32; off > 0; off >>= 1)
        acc += __shfl_down(acc, off, 64);

    __shared__ double sdata[THREADS / 64];
    int wave = threadIdx.x >> 6;
    if ((threadIdx.x & 63) == 0) sdata[wave] = acc;
    __syncthreads();

    if (threadIdx.x == 0) {
        double s = 0.0;
        #pragma unroll
        for (int w = 0; w < THREADS / 64; ++w) s += sdata[w];
        partials[blockIdx.x] = s;
    }
}

__global__ __launch_bounds__(256) void kl_finalize_kernel(
    const double* __restrict__ partials, int nblocks,
    float* __restrict__ out, double inv_nsamp, double dch)
{
    double acc = 0.0;
    for (int i = threadIdx.x; i < nblocks; i += blockDim.x)
        acc += partials[i];

    #pragma unroll
    for (int off = 32; off > 0; off >>= 1)
        acc += __shfl_down(acc, off, 64);

    __shared__ double sdata[4];
    int wave = threadIdx.x >> 6;
    if ((threadIdx.x & 63) == 0) sdata[wave] = acc;
    __syncthreads();

    if (threadIdx.x == 0) {
        double s = 0.0;
        #pragma unroll
        for (int w = 0; w < 4; ++w) s += sdata[w];
        out[0] = (float)(0.5 * (s * inv_nsamp - dch));
    }
}

extern "C" void kernel_launch(void* const* d_in, const int* in_sizes, int n_in,
                              void* d_out, int out_size, void* d_ws, size_t ws_size,
                              hipStream_t stream) {
    const float4* mp  = (const float4*)d_in[0];
    const float4* lsp = (const float4*)d_in[1];
    const float4* mq  = (const float4*)d_in[2];
    const float4* lsq = (const float4*)d_in[3];

    long n_total = (long)in_sizes[0];       // 29,491,200
    long n4 = n_total / 4;                  // exactly divisible
    const long d_ch = 3;
    double n_samples = (double)(n_total / d_ch);

    double* partials = (double*)d_ws;       // BLOCKS * 8 bytes = 16 KB

    kl_reduce_kernel<<<BLOCKS, THREADS, 0, stream>>>(mp, lsp, mq, lsq, partials, n4);
    kl_finalize_kernel<<<1, 256, 0, stream>>>(partials, BLOCKS, (float*)d_out,
                                              1.0 / n_samples, (double)d_ch);
}